// Round 2
// baseline (8153.448 us; speedup 1.0000x reference)
//
#include <hip/hip_runtime.h>
#include <hip/hip_fp16.h>

#define BB 128
#define II 64
#define SS 2048
#define HH 128
#define GG 512   // 4*H
#define OO 64
#define TT 32    // x time-tile width

typedef _Float16 f16x2 __attribute__((ext_vector_type(2)));
union F4H { float4 f4; f16x2 h[4]; };

__device__ __forceinline__ f16x2 pack2(float a, float b) {
    f16x2 r; r.x = (_Float16)a; r.y = (_Float16)b; return r;
}

__device__ __forceinline__ float dot2(f16x2 w, f16x2 v, float c) {
#if __has_builtin(__builtin_amdgcn_fdot2)
    return __builtin_amdgcn_fdot2(w, v, c, false);
#else
    return fmaf((float)w.x, (float)v.x, fmaf((float)w.y, (float)v.y, c));
#endif
}

__device__ __forceinline__ float sigm(float v) {
    return __builtin_amdgcn_rcpf(1.0f + __expf(-v));
}
__device__ __forceinline__ float tanh_f(float v) {
    float a = fabsf(v);
    float e = __expf(-2.0f * a);
    float r = (1.0f - e) * __builtin_amdgcn_rcpf(1.0f + e);
    return v < 0.0f ? -r : r;
}

// One block per batch element, 1024 threads.
// K-SPLIT BY LANE PAIR: j = tid>>1 owns gate column j, half = tid&1 owns
// half of every K-range. Per-thread register weights drop 192 -> 96 f16x2
// VGPRs, which FITS the 128-VGPR budget the allocator insists on for this
// kernel (two rounds of waves_per_eu attributes failed to raise it past 128;
// measured VGPR_Count=128 both times -> AGPR/spill traffic ~1000 cyc/step).
// Partial sums reduce with one __shfl_xor(p,1) - no LDS, no extra barrier.
// 16 waves/CU = 4/SIMD doubles occupancy for latency hiding.
__global__ void
__attribute__((amdgpu_flat_work_group_size(1024, 1024)))
__attribute__((amdgpu_waves_per_eu(4, 4)))
nlstm_scan(
    const float* __restrict__ x,
    const float* __restrict__ Wx_out, const float* __restrict__ Wh_out,
    const float* __restrict__ b_out,
    const float* __restrict__ Wx_in, const float* __restrict__ Wh_in,
    const float* __restrict__ b_in,
    const float* __restrict__ W_lin, const float* __restrict__ b_lin,
    float* __restrict__ out)
{
    const int b    = blockIdx.x;
    const int tid  = threadIdx.x;
    const int j    = tid >> 1;     // gate column 0..511
    const int half = tid & 1;      // K-split half

    // Wx_out fp16, chunk-major: chunk c (k=8c..8c+8) of column j at wxf[c*512+j].
    __shared__ __align__(16) float4 wxf[8 * 512];          // 64 KB
    // W_lin fp16, chunk-major padded: chunk c of row pn at wlf[c*66+pn].
    __shared__ __align__(16) float4 wlf[16 * 66];          // 16.5 KB
    // x time-tile, double-buffered, +1 pad breaks the column-read bank conflict.
    __shared__ float xt[2][II][TT + 1];                    // 16.9 KB
    __shared__ __align__(16) f16x2 xb[2][II / 2];          // x_t fp16, dbuf
    __shared__ __align__(16) f16x2 hb[HH / 2];             // h fp16
    __shared__ __align__(16) f16x2 xib[HH / 2];            // x_in fp16
    __shared__ __align__(16) f16x2 hib[HH / 2];            // h_in fp16
    __shared__ float cb[HH];                               // outer cell fp32
    __shared__ float cnb[HH];                              // inner cell fp32
    __shared__ float actO[GG];
    __shared__ float actI[GG];

    // ---- register-resident fp16 weight HALVES (column j) : 96 VGPRs ----
    f16x2 who[HH / 4];   // Wh_out col j, rows 64*half .. 64*half+63
    f16x2 wxi[HH / 4];   // Wx_in  col j, same half
    f16x2 whi[HH / 4];   // Wh_in  col j, same half
#pragma unroll
    for (int m = 0; m < HH / 4; ++m)
        who[m] = pack2(Wh_out[(64 * half + 2 * m) * GG + j],
                       Wh_out[(64 * half + 2 * m + 1) * GG + j]);
#pragma unroll
    for (int m = 0; m < HH / 4; ++m)
        wxi[m] = pack2(Wx_in[(64 * half + 2 * m) * GG + j],
                       Wx_in[(64 * half + 2 * m + 1) * GG + j]);
#pragma unroll
    for (int m = 0; m < HH / 4; ++m)
        whi[m] = pack2(Wh_in[(64 * half + 2 * m) * GG + j],
                       Wh_in[(64 * half + 2 * m + 1) * GG + j]);

    const float bo = b_out[j];
    const float bi = b_in[j];
    const int   pn = tid >> 4;     // projection output 0..63
    const int   ps = tid & 15;     // 16 threads per output, chunk c = ps
    const float bl = b_lin[pn];

    // Wx_out -> LDS fp16: thread (j,half) stages chunks 4*half..4*half+3
#pragma unroll
    for (int cc = 0; cc < 4; ++cc) {
        const int c = 4 * half + cc;
        F4H u;
#pragma unroll
        for (int q = 0; q < 4; ++q)
            u.h[q] = pack2(Wx_out[(8 * c + 2 * q) * GG + j],
                           Wx_out[(8 * c + 2 * q + 1) * GG + j]);
        wxf[c * 512 + j] = u.f4;
    }
    // W_lin -> LDS fp16 (1024 chunks, 1 per thread)
    {
        const int c = tid >> 6, n = tid & 63;
        F4H u;
#pragma unroll
        for (int q = 0; q < 4; ++q)
            u.h[q] = pack2(W_lin[n * HH + 8 * c + 2 * q],
                           W_lin[n * HH + 8 * c + 2 * q + 1]);
        wlf[c * 66 + n] = u.f4;
    }

    const float* xrow = x + (size_t)b * II * SS;   // x[b,i,t] = xrow[i*SS + t]
    float* orow = out + (size_t)b * SS * OO;

    // tile 0 -> xt[0]: threads 512..1023 load (coalesced float4)
    if (tid >= 512) {
        const int row = (tid - 512) >> 3, tc = (tid - 512) & 7;
        const float4 v = *(const float4*)(xrow + (size_t)row * SS + 4 * tc);
        float* dst = &xt[0][row][4 * tc];
        dst[0] = v.x; dst[1] = v.y; dst[2] = v.z; dst[3] = v.w;
    }
    if (tid < HH / 2) hb[tid] = pack2(0.f, 0.f);
    if (tid < HH) { cb[tid] = 0.f; cnb[tid] = 0.f; }
    if (tid >= 256 && tid < 256 + 32) {            // initial xb[0] pack (t=0)
        const int m = tid - 256;
        xb[0][m] = pack2(xrow[(2 * m) * SS], xrow[(2 * m + 1) * SS]);
    }
    __syncthreads();

    const float4* hb4 = (const float4*)hb;   // 16 chunks
    const float4* xi4 = (const float4*)xib;
    const float4* hi4 = (const float4*)hib;

#pragma unroll 1
    for (int t = 0; t < SS; ++t) {
        // ---- phase A: outer gates, col j, K-half `half` ----
        // x part: chunks 4*half..4*half+3 ; h part: chunks 8*half..8*half+7
        const float4* xcur = (const float4*)xb[t & 1];
        float a0 = 0.f, a1 = 0.f, a2 = 0.f, a3 = 0.f;
#pragma unroll
        for (int cc = 0; cc < 4; ++cc) {
            const int c = 4 * half + cc;
            F4H xu; xu.f4 = xcur[c];
            F4H wu; wu.f4 = wxf[c * 512 + j];
            a0 = dot2(wu.h[0], xu.h[0], a0);
            a1 = dot2(wu.h[1], xu.h[1], a1);
            a2 = dot2(wu.h[2], xu.h[2], a2);
            a3 = dot2(wu.h[3], xu.h[3], a3);
        }
#pragma unroll
        for (int cc = 0; cc < 8; ++cc) {
            F4H hu; hu.f4 = hb4[8 * half + cc];
            a0 = dot2(who[4 * cc + 0], hu.h[0], a0);
            a1 = dot2(who[4 * cc + 1], hu.h[1], a1);
            a2 = dot2(who[4 * cc + 2], hu.h[2], a2);
            a3 = dot2(who[4 * cc + 3], hu.h[3], a3);
        }
        {
            float s = (a0 + a1) + (a2 + a3);
            s += __shfl_xor(s, 1);            // combine K-halves (lane pair)
            const float acc = s + bo;
            if (half == 0)
                actO[j] = (j < 384) ? sigm(acc) : tanh_f(acc);
        }
        __syncthreads();   // B2

        // ---- phase B: inner-LSTM inputs ----
        if (tid < II) {  // x_in pairs
            xib[tid] = pack2(actO[2 * tid] * actO[384 + 2 * tid],
                             actO[2 * tid + 1] * actO[384 + 2 * tid + 1]);
        } else if (tid < II + HH / 2) {  // h_in pairs
            const int m = tid - II;
            hib[m] = pack2(actO[HH + 2 * m] * cb[2 * m],
                           actO[HH + 2 * m + 1] * cb[2 * m + 1]);
        }
        __syncthreads();   // B3

        // ---- phase C: inner gates, K-half `half` (chunks 8*half..8*half+7) ----
        float c0 = 0.f, c1 = 0.f, c2 = 0.f, c3 = 0.f;
#pragma unroll
        for (int cc = 0; cc < 8; ++cc) {
            F4H xu; xu.f4 = xi4[8 * half + cc];
            c0 = dot2(wxi[4 * cc + 0], xu.h[0], c0);
            c1 = dot2(wxi[4 * cc + 1], xu.h[1], c1);
            c2 = dot2(wxi[4 * cc + 2], xu.h[2], c2);
            c3 = dot2(wxi[4 * cc + 3], xu.h[3], c3);
        }
#pragma unroll
        for (int cc = 0; cc < 8; ++cc) {
            F4H hu; hu.f4 = hi4[8 * half + cc];
            c0 = dot2(whi[4 * cc + 0], hu.h[0], c0);
            c1 = dot2(whi[4 * cc + 1], hu.h[1], c1);
            c2 = dot2(whi[4 * cc + 2], hu.h[2], c2);
            c3 = dot2(whi[4 * cc + 3], hu.h[3], c3);
        }
        {
            float s2 = (c0 + c1) + (c2 + c3);
            s2 += __shfl_xor(s2, 1);          // combine K-halves
            const float acc2 = s2 + bi;
            if (half == 0)
                actI[j] = (j < 384) ? sigm(acc2) : tanh_f(acc2);
        }
        __syncthreads();   // B4

        // ---- phase D: state update + x staging for t+1 / tile prefetch ----
        // Tile T'=(t+2)>>5 loaded at (t&31)==30 by threads 512..1023 (idle
        // during state update) into the buffer that the step-(t+1) pack reads.
        const bool doTile = ((t & 31) == 30) && (t + 2 < SS) && (tid >= 512);
        float4 xld; int Tn = 0;
        if (doTile) {
            Tn = (t + 2) >> 5;
            const int row = (tid - 512) >> 3, tc = (tid - 512) & 7;
            xld = *(const float4*)(xrow + (size_t)row * SS + TT * Tn + 4 * tc);
        }
        if (tid < HH) {
            const float cn_new = actI[HH + tid] * cnb[tid] + actI[tid] * actI[384 + tid];
            const float c_new  = actI[2 * HH + tid] * tanh_f(cn_new);
            const float h_new  = actO[2 * HH + tid] * tanh_f(c_new);
            cnb[tid] = cn_new;
            cb[tid]  = c_new;
            ((_Float16*)hb)[tid] = (_Float16)h_new;
        } else if (tid < HH + 32) {   // pack xb for t+1 from the LDS tile
            const int m = tid - HH;
            const int tn = t + 1;     // tn==SS reads stale LDS, result unused
            const int tbn = (tn >> 5) & 1, ttn = tn & 31;
            xb[tn & 1][m] = pack2(xt[tbn][2 * m][ttn],
                                  xt[tbn][2 * m + 1][ttn]);
        }
        if (doTile) {
            const int row = (tid - 512) >> 3, tc = (tid - 512) & 7;
            float* dst = &xt[Tn & 1][row][4 * tc];
            dst[0] = xld.x; dst[1] = xld.y; dst[2] = xld.z; dst[3] = xld.w;
        }
        __syncthreads();   // B5

        // ---- phase E: fused projection, 16 threads per output row pn ----
        float p = 0.f;
        {
            F4H hu; hu.f4 = hb4[ps];
            F4H wu; wu.f4 = wlf[ps * 66 + pn];
            p = dot2(wu.h[0], hu.h[0], p);
            p = dot2(wu.h[1], hu.h[1], p);
            p = dot2(wu.h[2], hu.h[2], p);
            p = dot2(wu.h[3], hu.h[3], p);
        }
        p += __shfl_down(p, 8, 16);
        p += __shfl_down(p, 4, 16);
        p += __shfl_down(p, 2, 16);
        p += __shfl_down(p, 1, 16);
        if (ps == 0) orow[t * OO + pn] = p + bl;
    }
}

extern "C" void kernel_launch(void* const* d_in, const int* in_sizes, int n_in,
                              void* d_out, int out_size, void* d_ws, size_t ws_size,
                              hipStream_t stream) {
    (void)in_sizes; (void)n_in; (void)d_ws; (void)ws_size; (void)out_size;
    const float* x      = (const float*)d_in[0];
    const float* Wx_out = (const float*)d_in[1];
    const float* Wh_out = (const float*)d_in[2];
    const float* b_out  = (const float*)d_in[3];
    const float* Wx_in  = (const float*)d_in[4];
    const float* Wh_in  = (const float*)d_in[5];
    const float* b_in   = (const float*)d_in[6];
    const float* W_lin  = (const float*)d_in[7];
    const float* b_lin  = (const float*)d_in[8];
    float* out = (float*)d_out;

    nlstm_scan<<<dim3(BB), dim3(1024), 0, stream>>>(
        x, Wx_out, Wh_out, b_out, Wx_in, Wh_in, b_in, W_lin, b_lin, out);
}

// Round 3
// 6499.000 us; speedup vs baseline: 1.2546x; 1.2546x over previous
//
#include <hip/hip_runtime.h>
#include <hip/hip_fp16.h>

#define BB 128
#define II 64
#define SS 2048
#define HH 128
#define GG 512   // 4*H
#define OO 64
#define TT 32    // x time-tile width
#define JB 256   // gate columns per block (2 blocks per batch element)

typedef _Float16 f16x2 __attribute__((ext_vector_type(2)));
union F4H { float4 f4; f16x2 h[4]; };

__device__ __forceinline__ f16x2 pack2(float a, float b) {
    f16x2 r; r.x = (_Float16)a; r.y = (_Float16)b; return r;
}

__device__ __forceinline__ float dot2(f16x2 w, f16x2 v, float c) {
#if __has_builtin(__builtin_amdgcn_fdot2)
    return __builtin_amdgcn_fdot2(w, v, c, false);
#else
    return fmaf((float)w.x, (float)v.x, fmaf((float)w.y, (float)v.y, c));
#endif
}

__device__ __forceinline__ float sigm(float v) {
    return __builtin_amdgcn_rcpf(1.0f + __expf(-v));
}
__device__ __forceinline__ float tanh_f(float v) {
    float a = fabsf(v);
    float e = __expf(-2.0f * a);
    float r = (1.0f - e) * __builtin_amdgcn_rcpf(1.0f + e);
    return v < 0.0f ? -r : r;
}

// agent-scope relaxed atomics: sc-bit-correct cross-XCD, no bulk wbl2/inv
__device__ __forceinline__ unsigned ld_flag(const unsigned* p) {
    return __hip_atomic_load(p, __ATOMIC_RELAXED, __HIP_MEMORY_SCOPE_AGENT);
}
__device__ __forceinline__ void st_flag(unsigned* p, unsigned v) {
    __hip_atomic_store(p, v, __ATOMIC_RELAXED, __HIP_MEMORY_SCOPE_AGENT);
}
__device__ __forceinline__ float ld_ex(const float* p) {
    return __hip_atomic_load(p, __ATOMIC_RELAXED, __HIP_MEMORY_SCOPE_AGENT);
}
__device__ __forceinline__ void st_ex(float* p, float v) {
    __hip_atomic_store(p, v, __ATOMIC_RELAXED, __HIP_MEMORY_SCOPE_AGENT);
}

// ws layout (floats): exA[128][2][256] | exI[128][2][256] | flagA[128*2*16]u | flagI[...]u
#define EX_FLOATS (128 * 2 * JB)
#define FLAG_OFF_F (2 * EX_FLOATS)
#define FLAG_UINTS (128 * 2 * 16)

// 256 blocks: q = blk>>7 owns gate cols [256q,256q+256); batch = blk&127.
// Pair (blk, blk^128): same XCD under %8 round-robin -> L2-local exchange.
// Per-thread weights: 3 x 32 f16x2 = 96 VGPRs -> honest fit in the 128-VGPR
// budget the allocator grants 512-thread kernels (measured 3 rounds).
__global__ void __launch_bounds__(512)
nlstm_scan(
    const float* __restrict__ x,
    const float* __restrict__ Wx_out, const float* __restrict__ Wh_out,
    const float* __restrict__ b_out,
    const float* __restrict__ Wx_in, const float* __restrict__ Wh_in,
    const float* __restrict__ b_in,
    const float* __restrict__ W_lin, const float* __restrict__ b_lin,
    float* __restrict__ out, float* __restrict__ ws)
{
    const int blk  = blockIdx.x;
    const int q    = blk >> 7;       // 0: i,f cols | 1: o,g cols
    const int b    = blk & 127;      // batch element
    const int tid  = threadIdx.x;
    const int jl   = tid >> 1;       // local col 0..255
    const int half = tid & 1;        // K-split half
    const int jg   = q * JB + jl;    // global gate col 0..511

    __shared__ __align__(16) float4 wxf[8 * JB];        // Wx_out fp16, 32 KB
    __shared__ __align__(16) float4 wlf[16 * 34];       // W_lin rows 32q.., 8.5 KB
    __shared__ float xt[2][II][TT + 1];                 // x time-tile dbuf, 16.9 KB
    __shared__ __align__(16) f16x2 xb[2][II / 2];       // x_t fp16 dbuf
    __shared__ __align__(16) f16x2 hb[HH / 2];          // h fp16
    __shared__ __align__(16) f16x2 xib[HH / 2];         // x_in fp16
    __shared__ __align__(16) f16x2 hib[HH / 2];         // h_in fp16
    __shared__ float cb[HH];                            // outer cell fp32
    __shared__ float cnb[HH];                           // inner cell fp32
    __shared__ float actO_s[GG];                        // full outer acts
    __shared__ float actI_s[GG];                        // full inner acts

    // ---- register weights: col jg, K-half `half` : 96 VGPRs ----
    f16x2 who[32], wxi[32], whi[32];
#pragma unroll
    for (int m = 0; m < 32; ++m)
        who[m] = pack2(Wh_out[(64 * half + 2 * m) * GG + jg],
                       Wh_out[(64 * half + 2 * m + 1) * GG + jg]);
#pragma unroll
    for (int m = 0; m < 32; ++m)
        wxi[m] = pack2(Wx_in[(64 * half + 2 * m) * GG + jg],
                       Wx_in[(64 * half + 2 * m + 1) * GG + jg]);
#pragma unroll
    for (int m = 0; m < 32; ++m)
        whi[m] = pack2(Wh_in[(64 * half + 2 * m) * GG + jg],
                       Wh_in[(64 * half + 2 * m + 1) * GG + jg]);

    const float bo = b_out[jg];
    const float bi = b_in[jg];
    const int   pn_l = tid >> 4;     // 0..31 local projection row
    const int   ps   = tid & 15;     // chunk index
    const int   pn   = q * 32 + pn_l;
    const float bl   = b_lin[pn];

    // Wx_out -> LDS fp16: thread (jl,half) stages chunks 4*half..4*half+3
#pragma unroll
    for (int cc = 0; cc < 4; ++cc) {
        const int c = 4 * half + cc;
        F4H u;
#pragma unroll
        for (int q2 = 0; q2 < 4; ++q2)
            u.h[q2] = pack2(Wx_out[(8 * c + 2 * q2) * GG + jg],
                            Wx_out[(8 * c + 2 * q2 + 1) * GG + jg]);
        wxf[c * JB + jl] = u.f4;
    }
    // W_lin rows [32q,32q+32) -> LDS fp16 (512 chunks, 1 per thread)
    {
        const int n = tid >> 4, c = tid & 15;
        F4H u;
#pragma unroll
        for (int q2 = 0; q2 < 4; ++q2)
            u.h[q2] = pack2(W_lin[(32 * q + n) * HH + 8 * c + 2 * q2],
                            W_lin[(32 * q + n) * HH + 8 * c + 2 * q2 + 1]);
        wlf[c * 34 + n] = u.f4;
    }

    float*    exA   = ws;
    float*    exI   = ws + EX_FLOATS;
    unsigned* flagA = (unsigned*)(ws + FLAG_OFF_F);
    unsigned* flagI = flagA + FLAG_UINTS;
    const int myF = (b * 2 + q) * 16;
    const int prF = (b * 2 + (1 - q)) * 16;
    float* myA = exA + (b * 2 + q) * JB;
    float* prA = exA + (b * 2 + (1 - q)) * JB;
    float* myI = exI + (b * 2 + q) * JB;
    float* prI = exI + (b * 2 + (1 - q)) * JB;

    const float* xrow = x + (size_t)b * II * SS;   // x[b,i,t] = xrow[i*SS + t]
    float* orow = out + (size_t)b * SS * OO;

    {   // x tile 0 (all 512 threads, coalesced float4)
        const int row = tid >> 3, tc = tid & 7;
        const float4 v = *(const float4*)(xrow + (size_t)row * SS + 4 * tc);
        float* dst = &xt[0][row][4 * tc];
        dst[0] = v.x; dst[1] = v.y; dst[2] = v.z; dst[3] = v.w;
    }
    if (tid < HH / 2) hb[tid] = pack2(0.f, 0.f);
    if (tid < HH) { cb[tid] = 0.f; cnb[tid] = 0.f; }
    if (tid >= 256 && tid < 288) {                 // initial xb[0] pack (t=0)
        const int m = tid - 256;
        xb[0][m] = pack2(xrow[(2 * m) * SS], xrow[(2 * m + 1) * SS]);
    }
    __syncthreads();

    const float4* hb4 = (const float4*)hb;   // 16 chunks
    const float4* xi4 = (const float4*)xib;
    const float4* hi4 = (const float4*)hib;

#pragma unroll 1
    for (int t = 0; t < SS; ++t) {
        // ---- phase A: outer gates for local cols, K-half `half` ----
        const float4* xcur = (const float4*)xb[t & 1];
        float a0 = 0.f, a1 = 0.f, a2 = 0.f, a3 = 0.f;
#pragma unroll
        for (int cc = 0; cc < 4; ++cc) {
            const int c = 4 * half + cc;
            F4H xu; xu.f4 = xcur[c];
            F4H wu; wu.f4 = wxf[c * JB + jl];
            a0 = dot2(wu.h[0], xu.h[0], a0);
            a1 = dot2(wu.h[1], xu.h[1], a1);
            a2 = dot2(wu.h[2], xu.h[2], a2);
            a3 = dot2(wu.h[3], xu.h[3], a3);
        }
#pragma unroll
        for (int cc = 0; cc < 8; ++cc) {
            F4H hu; hu.f4 = hb4[8 * half + cc];
            a0 = dot2(who[4 * cc + 0], hu.h[0], a0);
            a1 = dot2(who[4 * cc + 1], hu.h[1], a1);
            a2 = dot2(who[4 * cc + 2], hu.h[2], a2);
            a3 = dot2(who[4 * cc + 3], hu.h[3], a3);
        }
        {
            float s = (a0 + a1) + (a2 + a3);
            s += __shfl_xor(s, 1);               // combine K-halves
            if (half == 0) {
                const float acc = s + bo;
                const float v = (jg < 384) ? sigm(acc) : tanh_f(acc);
                actO_s[jg] = v;
                st_ex(&myA[jl], v);
            }
        }
        asm volatile("s_waitcnt vmcnt(0)" ::: "memory");
        __syncthreads();                                           // S1
        if (tid == 0) st_flag(&flagA[myF], (unsigned)(t + 1));

        // ---- projection for t-1 (hides exchange-1 latency; hb = h(t-1)) ----
        if (t > 0) {
            float p = 0.f;
            F4H hu; hu.f4 = hb4[ps];
            F4H wu; wu.f4 = wlf[ps * 34 + pn_l];
            p = dot2(wu.h[0], hu.h[0], p);
            p = dot2(wu.h[1], hu.h[1], p);
            p = dot2(wu.h[2], hu.h[2], p);
            p = dot2(wu.h[3], hu.h[3], p);
            p += __shfl_down(p, 8, 16);
            p += __shfl_down(p, 4, 16);
            p += __shfl_down(p, 2, 16);
            p += __shfl_down(p, 1, 16);
            if (ps == 0) orow[(size_t)(t - 1) * OO + pn] = p + bl;
        }

        // ---- exchange 1: partner's outer acts ----
        if (tid == 0) { while (ld_flag(&flagA[prF]) < (unsigned)(t + 1)) {} }
        __syncthreads();                                           // S2
        if (tid < JB) actO_s[(1 - q) * JB + tid] = ld_ex(&prA[tid]);
        __syncthreads();                                           // S3

        // ---- phase B: inner-LSTM inputs ----
        if (tid < II) {
            xib[tid] = pack2(actO_s[2 * tid] * actO_s[384 + 2 * tid],
                             actO_s[2 * tid + 1] * actO_s[384 + 2 * tid + 1]);
        } else if (tid < II + HH / 2) {
            const int m = tid - II;
            hib[m] = pack2(actO_s[HH + 2 * m] * cb[2 * m],
                           actO_s[HH + 2 * m + 1] * cb[2 * m + 1]);
        }
        __syncthreads();                                           // S4

        // ---- phase C: inner gates for local cols, K-half `half` ----
        float c0 = 0.f, c1 = 0.f, c2 = 0.f, c3 = 0.f;
#pragma unroll
        for (int cc = 0; cc < 8; ++cc) {
            F4H xu; xu.f4 = xi4[8 * half + cc];
            c0 = dot2(wxi[4 * cc + 0], xu.h[0], c0);
            c1 = dot2(wxi[4 * cc + 1], xu.h[1], c1);
            c2 = dot2(wxi[4 * cc + 2], xu.h[2], c2);
            c3 = dot2(wxi[4 * cc + 3], xu.h[3], c3);
        }
#pragma unroll
        for (int cc = 0; cc < 8; ++cc) {
            F4H hu; hu.f4 = hi4[8 * half + cc];
            c0 = dot2(whi[4 * cc + 0], hu.h[0], c0);
            c1 = dot2(whi[4 * cc + 1], hu.h[1], c1);
            c2 = dot2(whi[4 * cc + 2], hu.h[2], c2);
            c3 = dot2(whi[4 * cc + 3], hu.h[3], c3);
        }
        {
            float s2 = (c0 + c1) + (c2 + c3);
            s2 += __shfl_xor(s2, 1);
            if (half == 0) {
                const float acc2 = s2 + bi;
                const float v = (jg < 384) ? sigm(acc2) : tanh_f(acc2);
                actI_s[jg] = v;
                st_ex(&myI[jl], v);
            }
        }
        asm volatile("s_waitcnt vmcnt(0)" ::: "memory");
        __syncthreads();                                           // S5
        if (tid == 0) st_flag(&flagI[myF], (unsigned)(t + 1));

        // ---- overlap window for exchange 2: x staging ----
        const bool doTile = ((t & 31) == 30) && (t + 2 < SS);
        float4 xld; int Tn = 0;
        if (doTile) {
            Tn = (t + 2) >> 5;
            const int row = tid >> 3, tc = tid & 7;
            xld = *(const float4*)(xrow + (size_t)row * SS + TT * Tn + 4 * tc);
        }
        if (tid >= 128 && tid < 160) {          // pack xb for t+1 from LDS tile
            const int m = tid - 128;
            const int tn = t + 1;               // tn==SS: stale read, unused
            const int tbn = (tn >> 5) & 1, ttn = tn & 31;
            xb[tn & 1][m] = pack2(xt[tbn][2 * m][ttn], xt[tbn][2 * m + 1][ttn]);
        }

        // ---- exchange 2: partner's inner acts ----
        if (tid == 0) { while (ld_flag(&flagI[prF]) < (unsigned)(t + 1)) {} }
        __syncthreads();                                           // S6
        if (tid < JB) actI_s[(1 - q) * JB + tid] = ld_ex(&prI[tid]);
        __syncthreads();                                           // S7

        // ---- phase D: state update (both blocks, identical inputs) ----
        if (tid < HH) {
            const float cn_new = actI_s[HH + tid] * cnb[tid] + actI_s[tid] * actI_s[384 + tid];
            const float c_new  = actI_s[2 * HH + tid] * tanh_f(cn_new);
            const float h_new  = actO_s[2 * HH + tid] * tanh_f(c_new);
            cnb[tid] = cn_new;
            cb[tid]  = c_new;
            ((_Float16*)hb)[tid] = (_Float16)h_new;
        }
        if (doTile) {
            const int row = tid >> 3, tc = tid & 7;
            float* dst = &xt[Tn & 1][row][4 * tc];
            dst[0] = xld.x; dst[1] = xld.y; dst[2] = xld.z; dst[3] = xld.w;
        }
        __syncthreads();                                           // S8
    }

    // ---- final projection for t = SS-1 ----
    {
        float p = 0.f;
        F4H hu; hu.f4 = hb4[ps];
        F4H wu; wu.f4 = wlf[ps * 34 + pn_l];
        p = dot2(wu.h[0], hu.h[0], p);
        p = dot2(wu.h[1], hu.h[1], p);
        p = dot2(wu.h[2], hu.h[2], p);
        p = dot2(wu.h[3], hu.h[3], p);
        p += __shfl_down(p, 8, 16);
        p += __shfl_down(p, 4, 16);
        p += __shfl_down(p, 2, 16);
        p += __shfl_down(p, 1, 16);
        if (ps == 0) orow[(size_t)(SS - 1) * OO + pn] = p + bl;
    }
}

extern "C" void kernel_launch(void* const* d_in, const int* in_sizes, int n_in,
                              void* d_out, int out_size, void* d_ws, size_t ws_size,
                              hipStream_t stream) {
    (void)in_sizes; (void)n_in; (void)ws_size; (void)out_size;
    const float* x      = (const float*)d_in[0];
    const float* Wx_out = (const float*)d_in[1];
    const float* Wh_out = (const float*)d_in[2];
    const float* b_out  = (const float*)d_in[3];
    const float* Wx_in  = (const float*)d_in[4];
    const float* Wh_in  = (const float*)d_in[5];
    const float* b_in   = (const float*)d_in[6];
    const float* W_lin  = (const float*)d_in[7];
    const float* b_lin  = (const float*)d_in[8];
    float* out = (float*)d_out;
    float* ws  = (float*)d_ws;

    // zero sync flags each launch (async, graph-capturable)
    hipMemsetAsync((char*)d_ws + FLAG_OFF_F * sizeof(float), 0,
                   2 * FLAG_UINTS * sizeof(unsigned), stream);

    nlstm_scan<<<dim3(2 * BB), dim3(512), 0, stream>>>(
        x, Wx_out, Wh_out, b_out, Wx_in, Wh_in, b_in, W_lin, b_lin, out, ws);
}